// Round 8
// baseline (148.765 us; speedup 1.0000x reference)
//
#include <hip/hip_runtime.h>
#include <hip/hip_bf16.h>

#define CH   128
#define HH   64
#define WW   64
#define OFFC 18

typedef __attribute__((ext_vector_type(8))) short bf16x8;
typedef __attribute__((ext_vector_type(4))) short bf16x4;
typedef __attribute__((ext_vector_type(4))) float f32x4;

static __device__ __forceinline__ unsigned short f2bf(float f) {
    __hip_bfloat16 h = __float2bfloat16(f);
    return *reinterpret_cast<unsigned short*>(&h);
}
static __device__ __forceinline__ float bf2f(unsigned short u) {
    union { unsigned int i; float f; } x; x.i = ((unsigned int)u) << 16;
    return x.f;
}

// ---------------------------------------------------------------------------
// Prep: pack all four weight tensors to bf16 MFMA A-fragment order AND
// convert x NCHW f32 -> NHWC bf16, one launch.  (unchanged)
// ---------------------------------------------------------------------------
__global__ __launch_bounds__(256) void prep_kernel(
    const float* __restrict__ x, unsigned short* __restrict__ xh,
    const float* __restrict__ wdc1, const float* __restrict__ wdc2,
    const float* __restrict__ wof1, const float* __restrict__ wof2,
    unsigned short* __restrict__ wpk1, unsigned short* __restrict__ wpk2,
    unsigned short* __restrict__ wpo1, unsigned short* __restrict__ wpo2)
{
    __shared__ float s[CH][WW + 1];
    int blk = blockIdx.x;
    int tid = threadIdx.x;

    if (blk < 1152) {
        const float* w = (blk < 576) ? wdc1 : wdc2;
        unsigned short* wp = (blk < 576) ? wpk1 : wpk2;
        int id = (blk % 576) * 256 + tid;          // 0..147455
        int j    = id & 7;
        int lane = (id >> 3) & 63;
        int ot   = (id >> 9) & 7;
        int kk   = (id >> 12) & 3;
        int k    = id >> 14;
        int o = ot * 16 + (lane & 15);
        int i = kk * 32 + (lane >> 4) * 8 + j;
        wp[id] = f2bf(w[(o * CH + i) * 9 + k]);
        return;
    }
    if (blk < 1440) {
        const float* w = (blk < 1296) ? wof1 : wof2;
        unsigned short* wp = (blk < 1296) ? wpo1 : wpo2;
        int id = ((blk - 1152) % 144) * 256 + tid; // 0..36863
        int j    = id & 7;
        int lane = (id >> 3) & 63;
        int mt   = (id >> 9) & 1;
        int kk   = (id >> 10) & 3;
        int k    = id >> 12;
        int o = mt * 16 + (lane & 15);
        int i = kk * 32 + (lane >> 4) * 8 + j;
        wp[id] = (o < OFFC) ? f2bf(w[(o * CH + i) * 9 + k]) : (unsigned short)0;
        return;
    }

    // ---- NCHW f32 -> NHWC bf16 ----------------------------------------
    int nb = blk - 1440;                     // b*64 + h
    const float* xb = x + ((size_t)(nb >> 6) * CH * HH + (nb & 63)) * WW;

    int c_off = tid >> 4, w0 = (tid & 15) * 4;
    #pragma unroll
    for (int it = 0; it < 8; ++it) {
        int c = it * 16 + c_off;
        float4 vv = *(const float4*)&xb[(size_t)c * HH * WW + w0];
        s[c][w0] = vv.x; s[c][w0 + 1] = vv.y; s[c][w0 + 2] = vv.z; s[c][w0 + 3] = vv.w;
    }
    __syncthreads();

    int w = tid & 63, c0 = (tid >> 6) * 32;
    unsigned short* dst = xh + ((size_t)nb * WW + w) * CH + c0;
    unsigned short tmp[32];
    #pragma unroll
    for (int j = 0; j < 32; ++j) tmp[j] = f2bf(s[c0 + j][w]);
    #pragma unroll
    for (int q = 0; q < 4; ++q)
        *(bf16x8*)(dst + q * 8) = *(const bf16x8*)(tmp + q * 8);
}

// ---------------------------------------------------------------------------
// Offset conv via MFMA implicit GEMM (unchanged).
// ---------------------------------------------------------------------------
__global__ __launch_bounds__(256) void off_conv_mfma_kernel(
    const unsigned short* __restrict__ xh,   // (B,64,64,128) bf16
    const unsigned short* __restrict__ wpo,  // packed A frags
    const float* __restrict__ bias,          // (18)
    unsigned short* __restrict__ offh)       // (B,18,64,64) bf16
{
    int wgid = blockIdx.x;                   // 512
    int blk  = (wgid & 7) * 64 + (wgid >> 3);
    int b = blk >> 6, oh = blk & 63;
    int tid = threadIdx.x;
    int lane = tid & 63;
    int nt = tid >> 6;
    int nl = lane & 15;
    int kg = lane >> 4;

    f32x4 acc0 = {0.f, 0.f, 0.f, 0.f}, acc1 = {0.f, 0.f, 0.f, 0.f};
    const unsigned short* xb = xh + (size_t)b * HH * WW * CH;

    for (int k = 0; k < 9; ++k) {
        int ky = k / 3, kx = k - ky * 3;
        int ih = oh - 1 + ky;
        if (ih < 0 || ih >= HH) continue;
        int iw = nt * 16 + nl + kx - 1;
        bool valid = (iw >= 0) && (iw < WW);
        const unsigned short* row = xb + ((size_t)ih * WW + (valid ? iw : 0)) * CH + kg * 8;
        const unsigned short* wk = wpo + (size_t)k * 4096;
        #pragma unroll
        for (int kk = 0; kk < 4; ++kk) {
            bf16x8 bfrag = {0, 0, 0, 0, 0, 0, 0, 0};
            if (valid) bfrag = *(const bf16x8*)(row + kk * 32);
            bf16x8 a0 = *(const bf16x8*)(wk + (kk * 2 + 0) * 512 + lane * 8);
            bf16x8 a1 = *(const bf16x8*)(wk + (kk * 2 + 1) * 512 + lane * 8);
            acc0 = __builtin_amdgcn_mfma_f32_16x16x32_bf16(a0, bfrag, acc0, 0, 0, 0);
            acc1 = __builtin_amdgcn_mfma_f32_16x16x32_bf16(a1, bfrag, acc1, 0, 0, 0);
        }
    }

    int ow = nt * 16 + nl;
    #pragma unroll
    for (int r = 0; r < 4; ++r) {
        int co = kg * 4 + r;                 // M-tile 0: co 0..15
        offh[(((size_t)b * OFFC + co) * HH + oh) * WW + ow] = f2bf(acc0[r] + bias[co]);
    }
    if (kg == 0) {
        #pragma unroll
        for (int r = 0; r < 2; ++r) {
            int co = 16 + r;                 // M-tile 1: co 16,17
            offh[(((size_t)b * OFFC + co) * HH + oh) * WW + ow] = f2bf(acc1[r] + bias[co]);
        }
    }
}

// ---------------------------------------------------------------------------
// Deformable conv (K=3, s1, pad 2, dil 2) via bf16 MFMA — BARRIER-FREE.
// Block = (b, oh) [XCD-swizzled by b], grid 512, 256 thr = 4 waves.
// Wave wv owns an EXCLUSIVE 16-ow strip (ow0 = 16*wv) x all 128 o channels
// (8 o-tiles). Each lane builds its own B-fragment in registers: lane l
// blends ci = kk*32 + (l>>4)*8 + j for ow = ow0 + (l&15) — exactly the
// mfma_16x16x32 B layout. No LDS, no __syncthreads in the main loop;
// straight-line 9-tap x 4-kk unroll lets the compiler pipeline gathers,
// blends and MFMAs across taps (pure ILP/TLP latency hiding).
// ---------------------------------------------------------------------------
__global__ __launch_bounds__(256, 2) void deform_direct_kernel(
    const unsigned short* __restrict__ xh,    // (B,64,64,128) bf16 (sampled)
    const unsigned short* __restrict__ offh,  // (B,18,64,64) bf16
    const unsigned short* __restrict__ wpk,   // packed A frags [9][4kk][8ot][512]
    const float* __restrict__ g, const float* __restrict__ beta,
    const float* __restrict__ m, const float* __restrict__ v,
    const float* __restrict__ residual,       // layer2 only
    unsigned short* __restrict__ out_h,       // layer1: NHWC bf16 out
    float* __restrict__ out_f)                // layer2: NCHW f32 out
{
    int wgid = blockIdx.x;                    // 512
    int blk  = (wgid & 7) * 64 + (wgid >> 3); // XCD n owns batch n
    int b = blk >> 6, oh = blk & 63;
    int tid = threadIdx.x, lane = tid & 63, wv = tid >> 6;

    int ow_g = wv * 16 + (lane & 15);         // this lane's output column
    int cig  = lane >> 4;                     // ci sub-group 0..3

    const unsigned short* xb = xh + (size_t)b * HH * WW * CH;

    // preload all 9 taps' offsets for my ow (18 independent scalar loads)
    float dyv[9], dxv[9];
    #pragma unroll
    for (int k = 0; k < 9; ++k) {
        dyv[k] = bf2f(offh[(((size_t)b * OFFC + 2 * k)     * HH + oh) * WW + ow_g]);
        dxv[k] = bf2f(offh[(((size_t)b * OFFC + 2 * k + 1) * HH + oh) * WW + ow_g]);
    }

    f32x4 acc[8];                             // 8 o-tiles x f32x4
    #pragma unroll
    for (int ot = 0; ot < 8; ++ot) acc[ot] = (f32x4){0.f, 0.f, 0.f, 0.f};

    #pragma unroll
    for (int k = 0; k < 9; ++k) {
        int ky = k / 3, kx = k - ky * 3;

        // bilinear coords for (oh, ow_g, tap k)
        float ys = (float)(oh - 2 + ky * 2) + dyv[k];
        float xs = (float)(ow_g - 2 + kx * 2) + dxv[k];
        float y0f = floorf(ys), x0f = floorf(xs);
        float fy = ys - y0f, fx = xs - x0f;
        int y0 = (int)y0f, x0i = (int)x0f;
        int y1 = y0 + 1, x1 = x0i + 1;
        bool vy0 = (y0 >= 0) & (y0 < HH), vy1 = (y1 >= 0) & (y1 < HH);
        bool vx0 = (x0i >= 0) & (x0i < WW), vx1 = (x1 >= 0) & (x1 < WW);
        int y0c = min(max(y0, 0), HH - 1), y1c = min(max(y1, 0), HH - 1);
        int x0c = min(max(x0i, 0), WW - 1), x1c = min(max(x1, 0), WW - 1);
        float cw0 = (1.f - fy) * (1.f - fx) * ((vy0 && vx0) ? 1.f : 0.f);
        float cw1 = (1.f - fy) * fx         * ((vy0 && vx1) ? 1.f : 0.f);
        float cw2 = fy * (1.f - fx)         * ((vy1 && vx0) ? 1.f : 0.f);
        float cw3 = fy * fx                 * ((vy1 && vx1) ? 1.f : 0.f);

        const unsigned short* p0 = xb + ((size_t)(y0c * WW + x0c)) * CH + cig * 8;
        const unsigned short* p1 = xb + ((size_t)(y0c * WW + x1c)) * CH + cig * 8;
        const unsigned short* p2 = xb + ((size_t)(y1c * WW + x0c)) * CH + cig * 8;
        const unsigned short* p3 = xb + ((size_t)(y1c * WW + x1c)) * CH + cig * 8;

        const unsigned short* wk = wpk + (size_t)k * 16384;

        #pragma unroll
        for (int kk = 0; kk < 4; ++kk) {
            // gather my 8 ci at each corner (4 x 16B loads, independent)
            bf16x8 g0 = *(const bf16x8*)(p0 + kk * 32);
            bf16x8 g1 = *(const bf16x8*)(p1 + kk * 32);
            bf16x8 g2 = *(const bf16x8*)(p2 + kk * 32);
            bf16x8 g3 = *(const bf16x8*)(p3 + kk * 32);

            // blend -> my B-fragment (in registers, no LDS)
            union { bf16x8 v8; unsigned short u[8]; } bfr;
            #pragma unroll
            for (int j = 0; j < 8; ++j) {
                float val = cw0 * bf2f((unsigned short)g0[j])
                          + cw1 * bf2f((unsigned short)g1[j])
                          + cw2 * bf2f((unsigned short)g2[j])
                          + cw3 * bf2f((unsigned short)g3[j]);
                bfr.u[j] = f2bf(val);
            }

            // 8 o-tiles: A-frag load (wave-uniform addr, L1-shared) + MFMA
            #pragma unroll
            for (int ot = 0; ot < 8; ++ot) {
                bf16x8 a = *(const bf16x8*)(wk + (size_t)(kk * 8 + ot) * 512 + lane * 8);
                acc[ot] = __builtin_amdgcn_mfma_f32_16x16x32_bf16(a, bfr.v8, acc[ot], 0, 0, 0);
            }
        }
    }

    // ---- epilogue (C layout: col = lane&15 = my ow; row = (lane>>4)*4+r) --
    if (out_h != nullptr) {
        // layer 1: BN + ReLU -> NHWC bf16
        #pragma unroll
        for (int ot = 0; ot < 8; ++ot) {
            int ob = ot * 16 + (lane >> 4) * 4;
            union { bf16x4 v4; unsigned short u[4]; } pk;
            #pragma unroll
            for (int r = 0; r < 4; ++r) {
                int o = ob + r;
                float iv = g[o] / sqrtf(v[o] + 1e-5f);
                float sh = beta[o] - m[o] * iv;
                pk.u[r] = f2bf(fmaxf(acc[ot][r] * iv + sh, 0.f));
            }
            *(bf16x4*)(out_h + ((size_t)(b * HH + oh) * WW + ow_g) * CH + ob) = pk.v4;
        }
    } else {
        // layer 2: BN + residual + ReLU -> NCHW f32
        #pragma unroll
        for (int ot = 0; ot < 8; ++ot) {
            #pragma unroll
            for (int r = 0; r < 4; ++r) {
                int o = ot * 16 + (lane >> 4) * 4 + r;
                float iv = g[o] / sqrtf(v[o] + 1e-5f);
                float sh = beta[o] - m[o] * iv;
                size_t idx = (((size_t)b * CH + o) * HH + oh) * WW + ow_g;
                float val = acc[ot][r] * iv + sh + residual[idx];
                out_f[idx] = fmaxf(val, 0.f);
            }
        }
    }
}

// ---------------------------------------------------------------------------
extern "C" void kernel_launch(void* const* d_in, const int* in_sizes, int n_in,
                              void* d_out, int out_size, void* d_ws, size_t ws_size,
                              hipStream_t stream)
{
    const float* x      = (const float*)d_in[0];
    const float* w_off1 = (const float*)d_in[1];
    const float* b_off1 = (const float*)d_in[2];
    const float* w_dc1  = (const float*)d_in[3];
    const float* g1     = (const float*)d_in[4];
    const float* beta1  = (const float*)d_in[5];
    const float* m1     = (const float*)d_in[6];
    const float* v1     = (const float*)d_in[7];
    const float* w_off2 = (const float*)d_in[8];
    const float* b_off2 = (const float*)d_in[9];
    const float* w_dc2  = (const float*)d_in[10];
    const float* g2     = (const float*)d_in[11];
    const float* beta2  = (const float*)d_in[12];
    const float* m2     = (const float*)d_in[13];
    const float* v2     = (const float*)d_in[14];
    float* out = (float*)d_out;

    char* ws = (char*)d_ws;
    unsigned short* xh    = (unsigned short*)ws;                  // 8,388,608 B
    unsigned short* out1h = (unsigned short*)(ws + 8388608);      // 8,388,608 B
    unsigned short* offh  = (unsigned short*)(ws + 16777216);     // 1,179,648 B
    unsigned short* wpk1  = (unsigned short*)(ws + 17956864);     //   294,912 B
    unsigned short* wpk2  = (unsigned short*)(ws + 18251776);     //   294,912 B
    unsigned short* wpo1  = (unsigned short*)(ws + 18546688);     //    73,728 B
    unsigned short* wpo2  = (unsigned short*)(ws + 18620416);     //    73,728 B
    // total 18,694,144 B

    prep_kernel<<<1952, 256, 0, stream>>>(x, xh, w_dc1, w_dc2, w_off1, w_off2,
                                          wpk1, wpk2, wpo1, wpo2);

    // Layer 1
    off_conv_mfma_kernel<<<512, 256, 0, stream>>>(xh, wpo1, b_off1, offh);
    deform_direct_kernel<<<512, 256, 0, stream>>>(xh, offh, wpk1,
                                                  g1, beta1, m1, v1,
                                                  nullptr, out1h, nullptr);
    // Layer 2
    off_conv_mfma_kernel<<<512, 256, 0, stream>>>(out1h, wpo2, b_off2, offh);
    deform_direct_kernel<<<512, 256, 0, stream>>>(out1h, offh, wpk2,
                                                  g2, beta2, m2, v2,
                                                  x, nullptr, out);
}

// Round 9
// 96.692 us; speedup vs baseline: 1.5385x; 1.5385x over previous
//
#include <hip/hip_runtime.h>
#include <hip/hip_bf16.h>

#define CH   128
#define HH   64
#define WW   64
#define OFFC 18

typedef __attribute__((ext_vector_type(8))) short bf16x8;
typedef __attribute__((ext_vector_type(4))) short bf16x4;
typedef __attribute__((ext_vector_type(4))) float f32x4;

static __device__ __forceinline__ unsigned short f2bf(float f) {
    __hip_bfloat16 h = __float2bfloat16(f);
    return *reinterpret_cast<unsigned short*>(&h);
}
static __device__ __forceinline__ float bf2f(unsigned short u) {
    union { unsigned int i; float f; } x; x.i = ((unsigned int)u) << 16;
    return x.f;
}

// ---------------------------------------------------------------------------
// Prep: pack all four weight tensors to bf16 MFMA A-fragment order AND
// convert x NCHW f32 -> NHWC bf16, one launch.  (unchanged)
// ---------------------------------------------------------------------------
__global__ __launch_bounds__(256) void prep_kernel(
    const float* __restrict__ x, unsigned short* __restrict__ xh,
    const float* __restrict__ wdc1, const float* __restrict__ wdc2,
    const float* __restrict__ wof1, const float* __restrict__ wof2,
    unsigned short* __restrict__ wpk1, unsigned short* __restrict__ wpk2,
    unsigned short* __restrict__ wpo1, unsigned short* __restrict__ wpo2)
{
    __shared__ float s[CH][WW + 1];
    int blk = blockIdx.x;
    int tid = threadIdx.x;

    if (blk < 1152) {
        const float* w = (blk < 576) ? wdc1 : wdc2;
        unsigned short* wp = (blk < 576) ? wpk1 : wpk2;
        int id = (blk % 576) * 256 + tid;          // 0..147455
        int j    = id & 7;
        int lane = (id >> 3) & 63;
        int ot   = (id >> 9) & 7;
        int kk   = (id >> 12) & 3;
        int k    = id >> 14;
        int o = ot * 16 + (lane & 15);
        int i = kk * 32 + (lane >> 4) * 8 + j;
        wp[id] = f2bf(w[(o * CH + i) * 9 + k]);
        return;
    }
    if (blk < 1440) {
        const float* w = (blk < 1296) ? wof1 : wof2;
        unsigned short* wp = (blk < 1296) ? wpo1 : wpo2;
        int id = ((blk - 1152) % 144) * 256 + tid; // 0..36863
        int j    = id & 7;
        int lane = (id >> 3) & 63;
        int mt   = (id >> 9) & 1;
        int kk   = (id >> 10) & 3;
        int k    = id >> 12;
        int o = mt * 16 + (lane & 15);
        int i = kk * 32 + (lane >> 4) * 8 + j;
        wp[id] = (o < OFFC) ? f2bf(w[(o * CH + i) * 9 + k]) : (unsigned short)0;
        return;
    }

    // ---- NCHW f32 -> NHWC bf16 ----------------------------------------
    int nb = blk - 1440;                     // b*64 + h
    const float* xb = x + ((size_t)(nb >> 6) * CH * HH + (nb & 63)) * WW;

    int c_off = tid >> 4, w0 = (tid & 15) * 4;
    #pragma unroll
    for (int it = 0; it < 8; ++it) {
        int c = it * 16 + c_off;
        float4 vv = *(const float4*)&xb[(size_t)c * HH * WW + w0];
        s[c][w0] = vv.x; s[c][w0 + 1] = vv.y; s[c][w0 + 2] = vv.z; s[c][w0 + 3] = vv.w;
    }
    __syncthreads();

    int w = tid & 63, c0 = (tid >> 6) * 32;
    unsigned short* dst = xh + ((size_t)nb * WW + w) * CH + c0;
    unsigned short tmp[32];
    #pragma unroll
    for (int j = 0; j < 32; ++j) tmp[j] = f2bf(s[c0 + j][w]);
    #pragma unroll
    for (int q = 0; q < 4; ++q)
        *(bf16x8*)(dst + q * 8) = *(const bf16x8*)(tmp + q * 8);
}

// ---------------------------------------------------------------------------
// Offset conv via MFMA implicit GEMM (unchanged).
// ---------------------------------------------------------------------------
__global__ __launch_bounds__(256) void off_conv_mfma_kernel(
    const unsigned short* __restrict__ xh,   // (B,64,64,128) bf16
    const unsigned short* __restrict__ wpo,  // packed A frags
    const float* __restrict__ bias,          // (18)
    unsigned short* __restrict__ offh)       // (B,18,64,64) bf16
{
    int wgid = blockIdx.x;                   // 512
    int blk  = (wgid & 7) * 64 + (wgid >> 3);
    int b = blk >> 6, oh = blk & 63;
    int tid = threadIdx.x;
    int lane = tid & 63;
    int nt = tid >> 6;
    int nl = lane & 15;
    int kg = lane >> 4;

    f32x4 acc0 = {0.f, 0.f, 0.f, 0.f}, acc1 = {0.f, 0.f, 0.f, 0.f};
    const unsigned short* xb = xh + (size_t)b * HH * WW * CH;

    for (int k = 0; k < 9; ++k) {
        int ky = k / 3, kx = k - ky * 3;
        int ih = oh - 1 + ky;
        if (ih < 0 || ih >= HH) continue;
        int iw = nt * 16 + nl + kx - 1;
        bool valid = (iw >= 0) && (iw < WW);
        const unsigned short* row = xb + ((size_t)ih * WW + (valid ? iw : 0)) * CH + kg * 8;
        const unsigned short* wk = wpo + (size_t)k * 4096;
        #pragma unroll
        for (int kk = 0; kk < 4; ++kk) {
            bf16x8 bfrag = {0, 0, 0, 0, 0, 0, 0, 0};
            if (valid) bfrag = *(const bf16x8*)(row + kk * 32);
            bf16x8 a0 = *(const bf16x8*)(wk + (kk * 2 + 0) * 512 + lane * 8);
            bf16x8 a1 = *(const bf16x8*)(wk + (kk * 2 + 1) * 512 + lane * 8);
            acc0 = __builtin_amdgcn_mfma_f32_16x16x32_bf16(a0, bfrag, acc0, 0, 0, 0);
            acc1 = __builtin_amdgcn_mfma_f32_16x16x32_bf16(a1, bfrag, acc1, 0, 0, 0);
        }
    }

    int ow = nt * 16 + nl;
    #pragma unroll
    for (int r = 0; r < 4; ++r) {
        int co = kg * 4 + r;                 // M-tile 0: co 0..15
        offh[(((size_t)b * OFFC + co) * HH + oh) * WW + ow] = f2bf(acc0[r] + bias[co]);
    }
    if (kg == 0) {
        #pragma unroll
        for (int r = 0; r < 2; ++r) {
            int co = 16 + r;                 // M-tile 1: co 16,17
            offh[(((size_t)b * OFFC + co) * HH + oh) * WW + ow] = f2bf(acc1[r] + bias[co]);
        }
    }
}

// ---------------------------------------------------------------------------
// Deformable conv (K=3, s1, pad 2, dil 2) via bf16 MFMA, NHWC input.
// OCCUPANCY-FIRST variant: no register A-prefetch (A read inline from
// L2-hot packed weights), offsets staged in LDS (not 18 VGPRs), gathers
// blended in two 8-ci chunks (16 live regs not 32).  launch_bounds(256,4)
// forces VGPR<=128 -> 4 waves/SIMD; grid 1024 -> 4 blocks/CU resident.
// Latency hiding comes from TLP (round-8 showed ILP-only fails; round 6
// showed 2 blocks/CU stalls 75%).
// ---------------------------------------------------------------------------
__global__ __launch_bounds__(256, 4) void deform_mfma2_kernel(
    const unsigned short* __restrict__ xh,    // (B,64,64,128) bf16 (sampled)
    const unsigned short* __restrict__ offh,  // (B,18,64,64) bf16
    const unsigned short* __restrict__ wpk,   // packed A frags [9][4kk][8ot][512]
    const float* __restrict__ g, const float* __restrict__ beta,
    const float* __restrict__ m, const float* __restrict__ v,
    const float* __restrict__ residual,       // layer2 only
    unsigned short* __restrict__ out_h,       // layer1: NHWC bf16 out
    float* __restrict__ out_f)                // layer2: NCHW f32 out
{
    __shared__ unsigned short sB[32 * 128];   // 8 KB [ow][ci], swizzled
    __shared__ float off_s[2 * 9][32];        // 2.25 KB offsets dy/dx per tap

    int wgid = blockIdx.x;                    // 1024
    int blk  = (wgid & 7) * 128 + (wgid >> 3);
    int owh = blk & 1, oh = (blk >> 1) & 63, b = blk >> 7;
    int ow0 = owh * 32;
    int tid = threadIdx.x, lane = tid & 63, wv = tid >> 6;

    int s_ow = tid >> 3;                      // 0..31 sampling ow
    int ci0  = (tid & 7) * 16;                // sampling ci block (16)
    int ow_g = ow0 + s_ow;

    const unsigned short* xb = xh + (size_t)b * HH * WW * CH;

    // ---- stage this row's offsets into LDS (576 bf16 -> f32) -----------
    for (int i = tid; i < 2 * 9 * 32; i += 256) {
        int co = i >> 5, owl = i & 31;
        off_s[co][owl] =
            bf2f(offh[(((size_t)b * OFFC + co) * HH + oh) * WW + ow0 + owl]);
    }
    __syncthreads();

    f32x4 acc[2][2];
    #pragma unroll
    for (int a = 0; a < 2; ++a)
        #pragma unroll
        for (int q = 0; q < 2; ++q) acc[a][q] = (f32x4){0.f, 0.f, 0.f, 0.f};

    for (int k = 0; k < 9; ++k) {
        int ky = k / 3, kx = k - ky * 3;

        // ---- coords (offsets from LDS) --------------------------------
        float dy = off_s[2 * k][s_ow];
        float dx = off_s[2 * k + 1][s_ow];
        float ys = (float)(oh - 2 + ky * 2) + dy;
        float xs = (float)(ow_g - 2 + kx * 2) + dx;
        float y0f = floorf(ys), x0f = floorf(xs);
        float fy = ys - y0f, fx = xs - x0f;
        int y0 = (int)y0f, x0i = (int)x0f;
        int y1 = y0 + 1, x1 = x0i + 1;
        bool vy0 = (y0 >= 0) & (y0 < HH), vy1 = (y1 >= 0) & (y1 < HH);
        bool vx0 = (x0i >= 0) & (x0i < WW), vx1 = (x1 >= 0) & (x1 < WW);
        int y0c = min(max(y0, 0), HH - 1), y1c = min(max(y1, 0), HH - 1);
        int x0c = min(max(x0i, 0), WW - 1), x1c = min(max(x1, 0), WW - 1);
        float cw0 = (1.f - fy) * (1.f - fx) * ((vy0 && vx0) ? 1.f : 0.f);
        float cw1 = (1.f - fy) * fx         * ((vy0 && vx1) ? 1.f : 0.f);
        float cw2 = fy * (1.f - fx)         * ((vy1 && vx0) ? 1.f : 0.f);
        float cw3 = fy * fx                 * ((vy1 && vx1) ? 1.f : 0.f);

        const unsigned short* p0 = xb + ((size_t)(y0c * WW + x0c)) * CH + ci0;
        const unsigned short* p1 = xb + ((size_t)(y0c * WW + x1c)) * CH + ci0;
        const unsigned short* p2 = xb + ((size_t)(y1c * WW + x0c)) * CH + ci0;
        const unsigned short* p3 = xb + ((size_t)(y1c * WW + x1c)) * CH + ci0;

        // ---- gather + blend in two 8-ci chunks (low register liveness) -
        int base = s_ow * 256 + ci0 * 2;
        int swz  = (s_ow & 7) << 4;
        #pragma unroll
        for (int q = 0; q < 2; ++q) {
            bf16x8 g0 = *(const bf16x8*)(p0 + q * 8);
            bf16x8 g1 = *(const bf16x8*)(p1 + q * 8);
            bf16x8 g2 = *(const bf16x8*)(p2 + q * 8);
            bf16x8 g3 = *(const bf16x8*)(p3 + q * 8);
            union { bf16x8 v8; unsigned short u[8]; } wu;
            #pragma unroll
            for (int j = 0; j < 8; ++j) {
                float val = cw0 * bf2f((unsigned short)g0[j])
                          + cw1 * bf2f((unsigned short)g1[j])
                          + cw2 * bf2f((unsigned short)g2[j])
                          + cw3 * bf2f((unsigned short)g3[j]);
                wu.u[j] = f2bf(val);
            }
            *(bf16x8*)((char*)sB + ((base + q * 16) ^ swz)) = wu.v8;
        }
        __syncthreads();

        // ---- MFMA: 4 K-chunks of 32 ci, A inline from global (L2-hot) --
        const unsigned short* wk = wpk + (size_t)k * 16384;
        #pragma unroll
        for (int kk = 0; kk < 4; ++kk) {
            bf16x8 a0 = *(const bf16x8*)(wk + (kk * 8 + 2 * wv)     * 512 + lane * 8);
            bf16x8 a1 = *(const bf16x8*)(wk + (kk * 8 + 2 * wv + 1) * 512 + lane * 8);
            #pragma unroll
            for (int owt = 0; owt < 2; ++owt) {
                int owl = owt * 16 + (lane & 15);
                int rbyte = (owl * 256 + (kk * 32 + (lane >> 4) * 8) * 2)
                            ^ ((owl & 7) << 4);
                bf16x8 bfv = *(const bf16x8*)((const char*)sB + rbyte);
                acc[0][owt] = __builtin_amdgcn_mfma_f32_16x16x32_bf16(
                                  a0, bfv, acc[0][owt], 0, 0, 0);
                acc[1][owt] = __builtin_amdgcn_mfma_f32_16x16x32_bf16(
                                  a1, bfv, acc[1][owt], 0, 0, 0);
            }
        }
        __syncthreads();
    }

    // ---- epilogue ------------------------------------------------------
    if (out_h != nullptr) {
        // layer 1: BN + ReLU -> NHWC bf16
        #pragma unroll
        for (int otl = 0; otl < 2; ++otl) {
            int ob = (2 * wv + otl) * 16 + (lane >> 4) * 4;
            float inv[4], sh[4];
            #pragma unroll
            for (int r = 0; r < 4; ++r) {
                int o = ob + r;
                float iv = g[o] / sqrtf(v[o] + 1e-5f);
                inv[r] = iv; sh[r] = beta[o] - m[o] * iv;
            }
            #pragma unroll
            for (int owt = 0; owt < 2; ++owt) {
                int ow = ow0 + owt * 16 + (lane & 15);
                union { bf16x4 v4; unsigned short u[4]; } pk;
                #pragma unroll
                for (int r = 0; r < 4; ++r) {
                    float val = acc[otl][owt][r] * inv[r] + sh[r];
                    pk.u[r] = f2bf(fmaxf(val, 0.f));
                }
                *(bf16x4*)(out_h + ((size_t)(b * HH + oh) * WW + ow) * CH + ob) = pk.v4;
            }
        }
    } else {
        // layer 2: BN + residual + ReLU -> NCHW f32
        #pragma unroll
        for (int otl = 0; otl < 2; ++otl) {
            #pragma unroll
            for (int r = 0; r < 4; ++r) {
                int o = (2 * wv + otl) * 16 + (lane >> 4) * 4 + r;
                float iv = g[o] / sqrtf(v[o] + 1e-5f);
                float sh = beta[o] - m[o] * iv;
                #pragma unroll
                for (int owt = 0; owt < 2; ++owt) {
                    int ow = ow0 + owt * 16 + (lane & 15);
                    size_t idx = (((size_t)b * CH + o) * HH + oh) * WW + ow;
                    float val = acc[otl][owt][r] * iv + sh + residual[idx];
                    out_f[idx] = fmaxf(val, 0.f);
                }
            }
        }
    }
}

// ---------------------------------------------------------------------------
extern "C" void kernel_launch(void* const* d_in, const int* in_sizes, int n_in,
                              void* d_out, int out_size, void* d_ws, size_t ws_size,
                              hipStream_t stream)
{
    const float* x      = (const float*)d_in[0];
    const float* w_off1 = (const float*)d_in[1];
    const float* b_off1 = (const float*)d_in[2];
    const float* w_dc1  = (const float*)d_in[3];
    const float* g1     = (const float*)d_in[4];
    const float* beta1  = (const float*)d_in[5];
    const float* m1     = (const float*)d_in[6];
    const float* v1     = (const float*)d_in[7];
    const float* w_off2 = (const float*)d_in[8];
    const float* b_off2 = (const float*)d_in[9];
    const float* w_dc2  = (const float*)d_in[10];
    const float* g2     = (const float*)d_in[11];
    const float* beta2  = (const float*)d_in[12];
    const float* m2     = (const float*)d_in[13];
    const float* v2     = (const float*)d_in[14];
    float* out = (float*)d_out;

    char* ws = (char*)d_ws;
    unsigned short* xh    = (unsigned short*)ws;                  // 8,388,608 B
    unsigned short* out1h = (unsigned short*)(ws + 8388608);      // 8,388,608 B
    unsigned short* offh  = (unsigned short*)(ws + 16777216);     // 1,179,648 B
    unsigned short* wpk1  = (unsigned short*)(ws + 17956864);     //   294,912 B
    unsigned short* wpk2  = (unsigned short*)(ws + 18251776);     //   294,912 B
    unsigned short* wpo1  = (unsigned short*)(ws + 18546688);     //    73,728 B
    unsigned short* wpo2  = (unsigned short*)(ws + 18620416);     //    73,728 B
    // total 18,694,144 B

    prep_kernel<<<1952, 256, 0, stream>>>(x, xh, w_dc1, w_dc2, w_off1, w_off2,
                                          wpk1, wpk2, wpo1, wpo2);

    // Layer 1
    off_conv_mfma_kernel<<<512, 256, 0, stream>>>(xh, wpo1, b_off1, offh);
    deform_mfma2_kernel<<<1024, 256, 0, stream>>>(xh, offh, wpk1,
                                                  g1, beta1, m1, v1,
                                                  nullptr, out1h, nullptr);
    // Layer 2
    off_conv_mfma_kernel<<<512, 256, 0, stream>>>(out1h, wpo2, b_off2, offh);
    deform_mfma2_kernel<<<1024, 256, 0, stream>>>(out1h, offh, wpk2,
                                                  g2, beta2, m2, v2,
                                                  x, nullptr, out);
}

// Round 10
// 95.201 us; speedup vs baseline: 1.5626x; 1.0157x over previous
//
#include <hip/hip_runtime.h>
#include <hip/hip_bf16.h>

#define CH   128
#define HH   64
#define WW   64
#define OFFC 18

typedef __attribute__((ext_vector_type(8))) short bf16x8;
typedef __attribute__((ext_vector_type(4))) short bf16x4;
typedef __attribute__((ext_vector_type(4))) float f32x4;

static __device__ __forceinline__ unsigned short f2bf(float f) {
    __hip_bfloat16 h = __float2bfloat16(f);
    return *reinterpret_cast<unsigned short*>(&h);
}
static __device__ __forceinline__ float bf2f(unsigned short u) {
    union { unsigned int i; float f; } x; x.i = ((unsigned int)u) << 16;
    return x.f;
}

// ---------------------------------------------------------------------------
// Prep: pack all four weight tensors to bf16 MFMA A-fragment order AND
// convert x NCHW f32 -> NHWC bf16, one launch.  (unchanged)
// ---------------------------------------------------------------------------
__global__ __launch_bounds__(256) void prep_kernel(
    const float* __restrict__ x, unsigned short* __restrict__ xh,
    const float* __restrict__ wdc1, const float* __restrict__ wdc2,
    const float* __restrict__ wof1, const float* __restrict__ wof2,
    unsigned short* __restrict__ wpk1, unsigned short* __restrict__ wpk2,
    unsigned short* __restrict__ wpo1, unsigned short* __restrict__ wpo2)
{
    __shared__ float s[CH][WW + 1];
    int blk = blockIdx.x;
    int tid = threadIdx.x;

    if (blk < 1152) {
        const float* w = (blk < 576) ? wdc1 : wdc2;
        unsigned short* wp = (blk < 576) ? wpk1 : wpk2;
        int id = (blk % 576) * 256 + tid;          // 0..147455
        int j    = id & 7;
        int lane = (id >> 3) & 63;
        int ot   = (id >> 9) & 7;
        int kk   = (id >> 12) & 3;
        int k    = id >> 14;
        int o = ot * 16 + (lane & 15);
        int i = kk * 32 + (lane >> 4) * 8 + j;
        wp[id] = f2bf(w[(o * CH + i) * 9 + k]);
        return;
    }
    if (blk < 1440) {
        const float* w = (blk < 1296) ? wof1 : wof2;
        unsigned short* wp = (blk < 1296) ? wpo1 : wpo2;
        int id = ((blk - 1152) % 144) * 256 + tid; // 0..36863
        int j    = id & 7;
        int lane = (id >> 3) & 63;
        int mt   = (id >> 9) & 1;
        int kk   = (id >> 10) & 3;
        int k    = id >> 12;
        int o = mt * 16 + (lane & 15);
        int i = kk * 32 + (lane >> 4) * 8 + j;
        wp[id] = (o < OFFC) ? f2bf(w[(o * CH + i) * 9 + k]) : (unsigned short)0;
        return;
    }

    // ---- NCHW f32 -> NHWC bf16 ----------------------------------------
    int nb = blk - 1440;                     // b*64 + h
    const float* xb = x + ((size_t)(nb >> 6) * CH * HH + (nb & 63)) * WW;

    int c_off = tid >> 4, w0 = (tid & 15) * 4;
    #pragma unroll
    for (int it = 0; it < 8; ++it) {
        int c = it * 16 + c_off;
        float4 vv = *(const float4*)&xb[(size_t)c * HH * WW + w0];
        s[c][w0] = vv.x; s[c][w0 + 1] = vv.y; s[c][w0 + 2] = vv.z; s[c][w0 + 3] = vv.w;
    }
    __syncthreads();

    int w = tid & 63, c0 = (tid >> 6) * 32;
    unsigned short* dst = xh + ((size_t)nb * WW + w) * CH + c0;
    unsigned short tmp[32];
    #pragma unroll
    for (int j = 0; j < 32; ++j) tmp[j] = f2bf(s[c0 + j][w]);
    #pragma unroll
    for (int q = 0; q < 4; ++q)
        *(bf16x8*)(dst + q * 8) = *(const bf16x8*)(tmp + q * 8);
}

// ---------------------------------------------------------------------------
// Offset conv via MFMA implicit GEMM (unchanged).
// ---------------------------------------------------------------------------
__global__ __launch_bounds__(256) void off_conv_mfma_kernel(
    const unsigned short* __restrict__ xh,   // (B,64,64,128) bf16
    const unsigned short* __restrict__ wpo,  // packed A frags
    const float* __restrict__ bias,          // (18)
    unsigned short* __restrict__ offh)       // (B,18,64,64) bf16
{
    int wgid = blockIdx.x;                   // 512
    int blk  = (wgid & 7) * 64 + (wgid >> 3);
    int b = blk >> 6, oh = blk & 63;
    int tid = threadIdx.x;
    int lane = tid & 63;
    int nt = tid >> 6;
    int nl = lane & 15;
    int kg = lane >> 4;

    f32x4 acc0 = {0.f, 0.f, 0.f, 0.f}, acc1 = {0.f, 0.f, 0.f, 0.f};
    const unsigned short* xb = xh + (size_t)b * HH * WW * CH;

    for (int k = 0; k < 9; ++k) {
        int ky = k / 3, kx = k - ky * 3;
        int ih = oh - 1 + ky;
        if (ih < 0 || ih >= HH) continue;
        int iw = nt * 16 + nl + kx - 1;
        bool valid = (iw >= 0) && (iw < WW);
        const unsigned short* row = xb + ((size_t)ih * WW + (valid ? iw : 0)) * CH + kg * 8;
        const unsigned short* wk = wpo + (size_t)k * 4096;
        #pragma unroll
        for (int kk = 0; kk < 4; ++kk) {
            bf16x8 bfrag = {0, 0, 0, 0, 0, 0, 0, 0};
            if (valid) bfrag = *(const bf16x8*)(row + kk * 32);
            bf16x8 a0 = *(const bf16x8*)(wk + (kk * 2 + 0) * 512 + lane * 8);
            bf16x8 a1 = *(const bf16x8*)(wk + (kk * 2 + 1) * 512 + lane * 8);
            acc0 = __builtin_amdgcn_mfma_f32_16x16x32_bf16(a0, bfrag, acc0, 0, 0, 0);
            acc1 = __builtin_amdgcn_mfma_f32_16x16x32_bf16(a1, bfrag, acc1, 0, 0, 0);
        }
    }

    int ow = nt * 16 + nl;
    #pragma unroll
    for (int r = 0; r < 4; ++r) {
        int co = kg * 4 + r;                 // M-tile 0: co 0..15
        offh[(((size_t)b * OFFC + co) * HH + oh) * WW + ow] = f2bf(acc0[r] + bias[co]);
    }
    if (kg == 0) {
        #pragma unroll
        for (int r = 0; r < 2; ++r) {
            int co = 16 + r;                 // M-tile 1: co 16,17
            offh[(((size_t)b * OFFC + co) * HH + oh) * WW + ow] = f2bf(acc1[r] + bias[co]);
        }
    }
}

// ---------------------------------------------------------------------------
// Deformable conv (K=3, s1, pad 2, dil 2) via bf16 MFMA, NHWC input.
// FULL-ROW blocks: N=64 ow per block, 512 threads (8 waves), grid 512.
// Rationale (r9 post-mortem): deform is L2-throughput-bound; A-fragment
// traffic scales with block count (294 KB table re-read per block). Full-row
// blocks halve A traffic per output (604 -> ~450 MB/dispatch) at unchanged
// 16 waves/CU occupancy. Wave wv owns o-tile ot=wv; 16 MFMA/tap/wave.
// ---------------------------------------------------------------------------
__global__ __launch_bounds__(512, 4) void deform_row_kernel(
    const unsigned short* __restrict__ xh,    // (B,64,64,128) bf16 (sampled)
    const unsigned short* __restrict__ offh,  // (B,18,64,64) bf16
    const unsigned short* __restrict__ wpk,   // packed A frags [9][4kk][8ot][512]
    const float* __restrict__ g, const float* __restrict__ beta,
    const float* __restrict__ m, const float* __restrict__ v,
    const float* __restrict__ residual,       // layer2 only
    unsigned short* __restrict__ out_h,       // layer1: NHWC bf16 out
    float* __restrict__ out_f)                // layer2: NCHW f32 out
{
    __shared__ unsigned short sB[64 * 128];   // 16 KB [ow][ci], swizzled
    __shared__ float off_s[OFFC][WW];         // 4.5 KB offsets (f32)

    int wgid = blockIdx.x;                    // 512
    int blk  = (wgid & 7) * 64 + (wgid >> 3); // XCD n owns batch n
    int b = blk >> 6, oh = blk & 63;
    int tid = threadIdx.x, lane = tid & 63, wv = tid >> 6;

    int s_ow = tid >> 3;                      // 0..63 sampling ow
    int ci0  = (tid & 7) * 16;                // sampling ci block (16)

    const unsigned short* xb = xh + (size_t)b * HH * WW * CH;

    // ---- stage this row's offsets into LDS (1152 bf16 -> f32) ----------
    for (int i = tid; i < OFFC * WW; i += 512) {
        int co = i >> 6, owl = i & 63;
        off_s[co][owl] =
            bf2f(offh[(((size_t)b * OFFC + co) * HH + oh) * WW + owl]);
    }
    __syncthreads();

    f32x4 acc[4];                             // 4 ow-tiles for my o-tile (wv)
    #pragma unroll
    for (int q = 0; q < 4; ++q) acc[q] = (f32x4){0.f, 0.f, 0.f, 0.f};

    for (int k = 0; k < 9; ++k) {
        int ky = k / 3, kx = k - ky * 3;

        // ---- coords (offsets from LDS) --------------------------------
        float dy = off_s[2 * k][s_ow];
        float dx = off_s[2 * k + 1][s_ow];
        float ys = (float)(oh - 2 + ky * 2) + dy;
        float xs = (float)(s_ow - 2 + kx * 2) + dx;
        float y0f = floorf(ys), x0f = floorf(xs);
        float fy = ys - y0f, fx = xs - x0f;
        int y0 = (int)y0f, x0i = (int)x0f;
        int y1 = y0 + 1, x1 = x0i + 1;
        bool vy0 = (y0 >= 0) & (y0 < HH), vy1 = (y1 >= 0) & (y1 < HH);
        bool vx0 = (x0i >= 0) & (x0i < WW), vx1 = (x1 >= 0) & (x1 < WW);
        int y0c = min(max(y0, 0), HH - 1), y1c = min(max(y1, 0), HH - 1);
        int x0c = min(max(x0i, 0), WW - 1), x1c = min(max(x1, 0), WW - 1);
        float cw0 = (1.f - fy) * (1.f - fx) * ((vy0 && vx0) ? 1.f : 0.f);
        float cw1 = (1.f - fy) * fx         * ((vy0 && vx1) ? 1.f : 0.f);
        float cw2 = fy * (1.f - fx)         * ((vy1 && vx0) ? 1.f : 0.f);
        float cw3 = fy * fx                 * ((vy1 && vx1) ? 1.f : 0.f);

        const unsigned short* p0 = xb + ((size_t)(y0c * WW + x0c)) * CH + ci0;
        const unsigned short* p1 = xb + ((size_t)(y0c * WW + x1c)) * CH + ci0;
        const unsigned short* p2 = xb + ((size_t)(y1c * WW + x0c)) * CH + ci0;
        const unsigned short* p3 = xb + ((size_t)(y1c * WW + x1c)) * CH + ci0;

        // ---- gather + blend in two 8-ci chunks -------------------------
        int base = s_ow * 256 + ci0 * 2;
        int swz  = (s_ow & 7) << 4;
        #pragma unroll
        for (int q = 0; q < 2; ++q) {
            bf16x8 g0 = *(const bf16x8*)(p0 + q * 8);
            bf16x8 g1 = *(const bf16x8*)(p1 + q * 8);
            bf16x8 g2 = *(const bf16x8*)(p2 + q * 8);
            bf16x8 g3 = *(const bf16x8*)(p3 + q * 8);
            union { bf16x8 v8; unsigned short u[8]; } wu;
            #pragma unroll
            for (int j = 0; j < 8; ++j) {
                float val = cw0 * bf2f((unsigned short)g0[j])
                          + cw1 * bf2f((unsigned short)g1[j])
                          + cw2 * bf2f((unsigned short)g2[j])
                          + cw3 * bf2f((unsigned short)g3[j]);
                wu.u[j] = f2bf(val);
            }
            *(bf16x8*)((char*)sB + ((base + q * 16) ^ swz)) = wu.v8;
        }
        __syncthreads();

        // ---- MFMA: wave wv = o-tile wv; 4 K-chunks x 4 ow-tiles --------
        const unsigned short* wk = wpk + (size_t)k * 16384;
        #pragma unroll
        for (int kk = 0; kk < 4; ++kk) {
            bf16x8 a = *(const bf16x8*)(wk + (size_t)(kk * 8 + wv) * 512 + lane * 8);
            #pragma unroll
            for (int owt = 0; owt < 4; ++owt) {
                int owl = owt * 16 + (lane & 15);
                int rbyte = (owl * 256 + (kk * 32 + (lane >> 4) * 8) * 2)
                            ^ ((owl & 7) << 4);
                bf16x8 bfv = *(const bf16x8*)((const char*)sB + rbyte);
                acc[owt] = __builtin_amdgcn_mfma_f32_16x16x32_bf16(
                               a, bfv, acc[owt], 0, 0, 0);
            }
        }
        __syncthreads();
    }

    // ---- epilogue: my o-tile = wv --------------------------------------
    int ob = wv * 16 + (lane >> 4) * 4;       // 4 consecutive o channels
    float inv[4], sh[4];
    #pragma unroll
    for (int r = 0; r < 4; ++r) {
        int o = ob + r;
        float iv = g[o] / sqrtf(v[o] + 1e-5f);
        inv[r] = iv; sh[r] = beta[o] - m[o] * iv;
    }

    if (out_h != nullptr) {
        // layer 1: BN + ReLU -> NHWC bf16
        #pragma unroll
        for (int owt = 0; owt < 4; ++owt) {
            int ow = owt * 16 + (lane & 15);
            union { bf16x4 v4; unsigned short u[4]; } pk;
            #pragma unroll
            for (int r = 0; r < 4; ++r) {
                float val = acc[owt][r] * inv[r] + sh[r];
                pk.u[r] = f2bf(fmaxf(val, 0.f));
            }
            *(bf16x4*)(out_h + ((size_t)(b * HH + oh) * WW + ow) * CH + ob) = pk.v4;
        }
    } else {
        // layer 2: BN + residual + ReLU -> NCHW f32
        #pragma unroll
        for (int r = 0; r < 4; ++r) {
            int o = ob + r;
            #pragma unroll
            for (int owt = 0; owt < 4; ++owt) {
                int ow = owt * 16 + (lane & 15);
                size_t idx = (((size_t)b * CH + o) * HH + oh) * WW + ow;
                float val = acc[owt][r] * inv[r] + sh[r] + residual[idx];
                out_f[idx] = fmaxf(val, 0.f);
            }
        }
    }
}

// ---------------------------------------------------------------------------
extern "C" void kernel_launch(void* const* d_in, const int* in_sizes, int n_in,
                              void* d_out, int out_size, void* d_ws, size_t ws_size,
                              hipStream_t stream)
{
    const float* x      = (const float*)d_in[0];
    const float* w_off1 = (const float*)d_in[1];
    const float* b_off1 = (const float*)d_in[2];
    const float* w_dc1  = (const float*)d_in[3];
    const float* g1     = (const float*)d_in[4];
    const float* beta1  = (const float*)d_in[5];
    const float* m1     = (const float*)d_in[6];
    const float* v1     = (const float*)d_in[7];
    const float* w_off2 = (const float*)d_in[8];
    const float* b_off2 = (const float*)d_in[9];
    const float* w_dc2  = (const float*)d_in[10];
    const float* g2     = (const float*)d_in[11];
    const float* beta2  = (const float*)d_in[12];
    const float* m2     = (const float*)d_in[13];
    const float* v2     = (const float*)d_in[14];
    float* out = (float*)d_out;

    char* ws = (char*)d_ws;
    unsigned short* xh    = (unsigned short*)ws;                  // 8,388,608 B
    unsigned short* out1h = (unsigned short*)(ws + 8388608);      // 8,388,608 B
    unsigned short* offh  = (unsigned short*)(ws + 16777216);     // 1,179,648 B
    unsigned short* wpk1  = (unsigned short*)(ws + 17956864);     //   294,912 B
    unsigned short* wpk2  = (unsigned short*)(ws + 18251776);     //   294,912 B
    unsigned short* wpo1  = (unsigned short*)(ws + 18546688);     //    73,728 B
    unsigned short* wpo2  = (unsigned short*)(ws + 18620416);     //    73,728 B
    // total 18,694,144 B

    prep_kernel<<<1952, 256, 0, stream>>>(x, xh, w_dc1, w_dc2, w_off1, w_off2,
                                          wpk1, wpk2, wpo1, wpo2);

    // Layer 1
    off_conv_mfma_kernel<<<512, 256, 0, stream>>>(xh, wpo1, b_off1, offh);
    deform_row_kernel<<<512, 512, 0, stream>>>(xh, offh, wpk1,
                                               g1, beta1, m1, v1,
                                               nullptr, out1h, nullptr);
    // Layer 2
    off_conv_mfma_kernel<<<512, 256, 0, stream>>>(out1h, wpo2, b_off2, offh);
    deform_row_kernel<<<512, 512, 0, stream>>>(out1h, offh, wpk2,
                                               g2, beta2, m2, v2,
                                               x, nullptr, out);
}

// Round 11
// 91.564 us; speedup vs baseline: 1.6247x; 1.0397x over previous
//
#include <hip/hip_runtime.h>
#include <hip/hip_bf16.h>

#define CH   128
#define HH   64
#define WW   64
#define OFFC 18

typedef __attribute__((ext_vector_type(8))) short bf16x8;
typedef __attribute__((ext_vector_type(4))) short bf16x4;
typedef __attribute__((ext_vector_type(4))) float f32x4;

static __device__ __forceinline__ unsigned short f2bf(float f) {
    __hip_bfloat16 h = __float2bfloat16(f);
    return *reinterpret_cast<unsigned short*>(&h);
}
static __device__ __forceinline__ float bf2f(unsigned short u) {
    union { unsigned int i; float f; } x; x.i = ((unsigned int)u) << 16;
    return x.f;
}

// ---------------------------------------------------------------------------
// Prep: pack weights + NCHW->NHWC (unchanged).
// ---------------------------------------------------------------------------
__global__ __launch_bounds__(256) void prep_kernel(
    const float* __restrict__ x, unsigned short* __restrict__ xh,
    const float* __restrict__ wdc1, const float* __restrict__ wdc2,
    const float* __restrict__ wof1, const float* __restrict__ wof2,
    unsigned short* __restrict__ wpk1, unsigned short* __restrict__ wpk2,
    unsigned short* __restrict__ wpo1, unsigned short* __restrict__ wpo2)
{
    __shared__ float s[CH][WW + 1];
    int blk = blockIdx.x;
    int tid = threadIdx.x;

    if (blk < 1152) {
        const float* w = (blk < 576) ? wdc1 : wdc2;
        unsigned short* wp = (blk < 576) ? wpk1 : wpk2;
        int id = (blk % 576) * 256 + tid;          // 0..147455
        int j    = id & 7;
        int lane = (id >> 3) & 63;
        int ot   = (id >> 9) & 7;
        int kk   = (id >> 12) & 3;
        int k    = id >> 14;
        int o = ot * 16 + (lane & 15);
        int i = kk * 32 + (lane >> 4) * 8 + j;
        wp[id] = f2bf(w[(o * CH + i) * 9 + k]);
        return;
    }
    if (blk < 1440) {
        const float* w = (blk < 1296) ? wof1 : wof2;
        unsigned short* wp = (blk < 1296) ? wpo1 : wpo2;
        int id = ((blk - 1152) % 144) * 256 + tid; // 0..36863
        int j    = id & 7;
        int lane = (id >> 3) & 63;
        int mt   = (id >> 9) & 1;
        int kk   = (id >> 10) & 3;
        int k    = id >> 12;
        int o = mt * 16 + (lane & 15);
        int i = kk * 32 + (lane >> 4) * 8 + j;
        wp[id] = (o < OFFC) ? f2bf(w[(o * CH + i) * 9 + k]) : (unsigned short)0;
        return;
    }

    int nb = blk - 1440;                     // b*64 + h
    const float* xb = x + ((size_t)(nb >> 6) * CH * HH + (nb & 63)) * WW;

    int c_off = tid >> 4, w0 = (tid & 15) * 4;
    #pragma unroll
    for (int it = 0; it < 8; ++it) {
        int c = it * 16 + c_off;
        float4 vv = *(const float4*)&xb[(size_t)c * HH * WW + w0];
        s[c][w0] = vv.x; s[c][w0 + 1] = vv.y; s[c][w0 + 2] = vv.z; s[c][w0 + 3] = vv.w;
    }
    __syncthreads();

    int w = tid & 63, c0 = (tid >> 6) * 32;
    unsigned short* dst = xh + ((size_t)nb * WW + w) * CH + c0;
    unsigned short tmp[32];
    #pragma unroll
    for (int j = 0; j < 32; ++j) tmp[j] = f2bf(s[c0 + j][w]);
    #pragma unroll
    for (int q = 0; q < 4; ++q)
        *(bf16x8*)(dst + q * 8) = *(const bf16x8*)(tmp + q * 8);
}

// ---------------------------------------------------------------------------
// Offset conv via MFMA implicit GEMM (unchanged).
// ---------------------------------------------------------------------------
__global__ __launch_bounds__(256) void off_conv_mfma_kernel(
    const unsigned short* __restrict__ xh,
    const unsigned short* __restrict__ wpo,
    const float* __restrict__ bias,
    unsigned short* __restrict__ offh)
{
    int wgid = blockIdx.x;                   // 512
    int blk  = (wgid & 7) * 64 + (wgid >> 3);
    int b = blk >> 6, oh = blk & 63;
    int tid = threadIdx.x;
    int lane = tid & 63;
    int nt = tid >> 6;
    int nl = lane & 15;
    int kg = lane >> 4;

    f32x4 acc0 = {0.f, 0.f, 0.f, 0.f}, acc1 = {0.f, 0.f, 0.f, 0.f};
    const unsigned short* xb = xh + (size_t)b * HH * WW * CH;

    for (int k = 0; k < 9; ++k) {
        int ky = k / 3, kx = k - ky * 3;
        int ih = oh - 1 + ky;
        if (ih < 0 || ih >= HH) continue;
        int iw = nt * 16 + nl + kx - 1;
        bool valid = (iw >= 0) && (iw < WW);
        const unsigned short* row = xb + ((size_t)ih * WW + (valid ? iw : 0)) * CH + kg * 8;
        const unsigned short* wk = wpo + (size_t)k * 4096;
        #pragma unroll
        for (int kk = 0; kk < 4; ++kk) {
            bf16x8 bfrag = {0, 0, 0, 0, 0, 0, 0, 0};
            if (valid) bfrag = *(const bf16x8*)(row + kk * 32);
            bf16x8 a0 = *(const bf16x8*)(wk + (kk * 2 + 0) * 512 + lane * 8);
            bf16x8 a1 = *(const bf16x8*)(wk + (kk * 2 + 1) * 512 + lane * 8);
            acc0 = __builtin_amdgcn_mfma_f32_16x16x32_bf16(a0, bfrag, acc0, 0, 0, 0);
            acc1 = __builtin_amdgcn_mfma_f32_16x16x32_bf16(a1, bfrag, acc1, 0, 0, 0);
        }
    }

    int ow = nt * 16 + nl;
    #pragma unroll
    for (int r = 0; r < 4; ++r) {
        int co = kg * 4 + r;
        offh[(((size_t)b * OFFC + co) * HH + oh) * WW + ow] = f2bf(acc0[r] + bias[co]);
    }
    if (kg == 0) {
        #pragma unroll
        for (int r = 0; r < 2; ++r) {
            int co = 16 + r;
            offh[(((size_t)b * OFFC + co) * HH + oh) * WW + ow] = f2bf(acc1[r] + bias[co]);
        }
    }
}

// ---------------------------------------------------------------------------
// Deformable conv via bf16 MFMA — PRODUCER/CONSUMER wave specialization.
// Grid 512 (b,oh), 512 thr = 8 waves. Waves 0-3: samplers (gather+blend into
// 2-deep LDS ring). Waves 4-7: MFMA consumers. NO __syncthreads in main loop
// (would drain vmcnt); sync via LDS atomic epoch counters (release/acquire).
// Producer thread: (s_ow = tid>>3 in 0..31, serving ow and ow+32; cig=tid&7),
// gathers 16B contiguous chunks (ci = q*64 + cig*8) so each load instruction
// touches 8 whole 128B lines. Consumer wave cw owns o-tiles {2cw, 2cw+1}:
// per tap 8 A-loads (global, L1-hot) + 16 ds_read + 32 MFMA under setprio(1).
// ---------------------------------------------------------------------------
__global__ __launch_bounds__(512, 4) void deform_pc_kernel(
    const unsigned short* __restrict__ xh,    // (B,64,64,128) bf16 (sampled)
    const unsigned short* __restrict__ offh,  // (B,18,64,64) bf16
    const unsigned short* __restrict__ wpk,   // packed A frags [9][4kk][8ot][512]
    const float* __restrict__ g, const float* __restrict__ beta,
    const float* __restrict__ m, const float* __restrict__ v,
    const float* __restrict__ residual,       // layer2 only
    unsigned short* __restrict__ out_h,       // layer1: NHWC bf16 out
    float* __restrict__ out_f)                // layer2: NCHW f32 out
{
    __shared__ unsigned short sB[2][64 * 128]; // 32 KB ring [buf][ow][ci] swz
    __shared__ float off_s[OFFC][WW];          // 4.5 KB offsets (f32)
    __shared__ int flg[4];                     // [0,1]=prod_cnt [2,3]=cons_cnt

    int wgid = blockIdx.x;                    // 512
    int blk  = (wgid & 7) * 64 + (wgid >> 3); // XCD n owns batch n
    int b = blk >> 6, oh = blk & 63;
    int tid = threadIdx.x, lane = tid & 63, wv = tid >> 6;

    const unsigned short* xb = xh + (size_t)b * HH * WW * CH;

    // stage offsets + init flags, single barrier (before any loop loads)
    for (int i = tid; i < OFFC * WW; i += 512) {
        int co = i >> 6, owl = i & 63;
        off_s[co][owl] =
            bf2f(offh[(((size_t)b * OFFC + co) * HH + oh) * WW + owl]);
    }
    if (tid < 4) flg[tid] = 0;
    __syncthreads();

    if (wv < 4) {
        // =================== PRODUCER =====================================
        int s_ow = tid >> 3;                  // 0..31 (also serves +32)
        int cig  = tid & 7;                   // 16B chunk id within pixel

        for (int k = 0; k < 9; ++k) {
            int buf = k & 1;
            if (k >= 2) {
                int tgt = 4 * (k >> 1);       // consumers done with tap k-2
                while (__hip_atomic_load(&flg[2 + buf], __ATOMIC_ACQUIRE,
                                         __HIP_MEMORY_SCOPE_WORKGROUP) < tgt)
                    __builtin_amdgcn_s_sleep(1);
            }
            int ky = k / 3, kx = k - ky * 3;

            #pragma unroll
            for (int w2 = 0; w2 < 2; ++w2) {
                int ow = s_ow + w2 * 32;
                float dy = off_s[2 * k][ow];
                float dx = off_s[2 * k + 1][ow];
                float ys = (float)(oh - 2 + ky * 2) + dy;
                float xs = (float)(ow - 2 + kx * 2) + dx;
                float y0f = floorf(ys), x0f = floorf(xs);
                float fy = ys - y0f, fx = xs - x0f;
                int y0 = (int)y0f, x0i = (int)x0f;
                int y1 = y0 + 1, x1 = x0i + 1;
                bool vy0 = (y0 >= 0) & (y0 < HH), vy1 = (y1 >= 0) & (y1 < HH);
                bool vx0 = (x0i >= 0) & (x0i < WW), vx1 = (x1 >= 0) & (x1 < WW);
                int y0c = min(max(y0, 0), HH - 1), y1c = min(max(y1, 0), HH - 1);
                int x0c = min(max(x0i, 0), WW - 1), x1c = min(max(x1, 0), WW - 1);
                float cw0 = (1.f - fy) * (1.f - fx) * ((vy0 && vx0) ? 1.f : 0.f);
                float cw1 = (1.f - fy) * fx         * ((vy0 && vx1) ? 1.f : 0.f);
                float cw2 = fy * (1.f - fx)         * ((vy1 && vx0) ? 1.f : 0.f);
                float cw3 = fy * fx                 * ((vy1 && vx1) ? 1.f : 0.f);

                const unsigned short* p0 = xb + ((size_t)(y0c * WW + x0c)) * CH + cig * 8;
                const unsigned short* p1 = xb + ((size_t)(y0c * WW + x1c)) * CH + cig * 8;
                const unsigned short* p2 = xb + ((size_t)(y1c * WW + x0c)) * CH + cig * 8;
                const unsigned short* p3 = xb + ((size_t)(y1c * WW + x1c)) * CH + cig * 8;

                int swz = (ow & 7) << 4;
                #pragma unroll
                for (int q = 0; q < 2; ++q) {
                    int cie = q * 64 + cig * 8;        // element index
                    bf16x8 g0 = *(const bf16x8*)(p0 + q * 64);
                    bf16x8 g1 = *(const bf16x8*)(p1 + q * 64);
                    bf16x8 g2 = *(const bf16x8*)(p2 + q * 64);
                    bf16x8 g3 = *(const bf16x8*)(p3 + q * 64);
                    union { bf16x8 v8; unsigned short u[8]; } wu;
                    #pragma unroll
                    for (int j = 0; j < 8; ++j) {
                        float val = cw0 * bf2f((unsigned short)g0[j])
                                  + cw1 * bf2f((unsigned short)g1[j])
                                  + cw2 * bf2f((unsigned short)g2[j])
                                  + cw3 * bf2f((unsigned short)g3[j]);
                        wu.u[j] = f2bf(val);
                    }
                    int byte = (ow * 256 + cie * 2) ^ swz;
                    *(bf16x8*)((char*)sB[buf] + byte) = wu.v8;
                }
            }
            // make LDS writes visible, then post
            asm volatile("s_waitcnt lgkmcnt(0)" ::: "memory");
            if (lane == 0)
                __hip_atomic_fetch_add(&flg[buf], 1, __ATOMIC_RELEASE,
                                       __HIP_MEMORY_SCOPE_WORKGROUP);
        }
    } else {
        // =================== CONSUMER =====================================
        int cw = wv - 4;                      // 0..3: o-tiles {2cw, 2cw+1}
        f32x4 acc[2][4];
        #pragma unroll
        for (int a = 0; a < 2; ++a)
            #pragma unroll
            for (int q = 0; q < 4; ++q) acc[a][q] = (f32x4){0.f, 0.f, 0.f, 0.f};

        for (int k = 0; k < 9; ++k) {
            int buf = k & 1;
            int tgt = 4 * ((k >> 1) + 1);     // producers done with tap k
            while (__hip_atomic_load(&flg[buf], __ATOMIC_ACQUIRE,
                                     __HIP_MEMORY_SCOPE_WORKGROUP) < tgt)
                __builtin_amdgcn_s_sleep(1);

            const unsigned short* wk = wpk + (size_t)k * 16384;
            __builtin_amdgcn_s_setprio(1);
            #pragma unroll
            for (int kk = 0; kk < 4; ++kk) {
                bf16x8 a0 = *(const bf16x8*)(wk + (size_t)(kk * 8 + 2 * cw)     * 512 + lane * 8);
                bf16x8 a1 = *(const bf16x8*)(wk + (size_t)(kk * 8 + 2 * cw + 1) * 512 + lane * 8);
                #pragma unroll
                for (int owt = 0; owt < 4; ++owt) {
                    int owl = owt * 16 + (lane & 15);
                    int rbyte = (owl * 256 + (kk * 32 + (lane >> 4) * 8) * 2)
                                ^ ((owl & 7) << 4);
                    bf16x8 bfv = *(const bf16x8*)((const char*)sB[buf] + rbyte);
                    acc[0][owt] = __builtin_amdgcn_mfma_f32_16x16x32_bf16(
                                      a0, bfv, acc[0][owt], 0, 0, 0);
                    acc[1][owt] = __builtin_amdgcn_mfma_f32_16x16x32_bf16(
                                      a1, bfv, acc[1][owt], 0, 0, 0);
                }
            }
            __builtin_amdgcn_s_setprio(0);
            // ds_reads retired (compiler waits lgkmcnt before MFMA) -> free buf
            asm volatile("s_waitcnt lgkmcnt(0)" ::: "memory");
            if (lane == 0)
                __hip_atomic_fetch_add(&flg[2 + buf], 1, __ATOMIC_RELEASE,
                                       __HIP_MEMORY_SCOPE_WORKGROUP);
        }

        // ---- epilogue (consumers hold all 128 o across 4 waves) --------
        #pragma unroll
        for (int otl = 0; otl < 2; ++otl) {
            int ob = (2 * cw + otl) * 16 + (lane >> 4) * 4;
            float inv[4], sh[4];
            #pragma unroll
            for (int r = 0; r < 4; ++r) {
                int o = ob + r;
                float iv = g[o] / sqrtf(v[o] + 1e-5f);
                inv[r] = iv; sh[r] = beta[o] - m[o] * iv;
            }
            if (out_h != nullptr) {
                #pragma unroll
                for (int owt = 0; owt < 4; ++owt) {
                    int ow = owt * 16 + (lane & 15);
                    union { bf16x4 v4; unsigned short u[4]; } pk;
                    #pragma unroll
                    for (int r = 0; r < 4; ++r) {
                        float val = acc[otl][owt][r] * inv[r] + sh[r];
                        pk.u[r] = f2bf(fmaxf(val, 0.f));
                    }
                    *(bf16x4*)(out_h + ((size_t)(b * HH + oh) * WW + ow) * CH + ob) = pk.v4;
                }
            } else {
                #pragma unroll
                for (int r = 0; r < 4; ++r) {
                    int o = ob + r;
                    #pragma unroll
                    for (int owt = 0; owt < 4; ++owt) {
                        int ow = owt * 16 + (lane & 15);
                        size_t idx = (((size_t)b * CH + o) * HH + oh) * WW + ow;
                        float val = acc[otl][owt][r] * inv[r] + sh[r] + residual[idx];
                        out_f[idx] = fmaxf(val, 0.f);
                    }
                }
            }
        }
    }
}

// ---------------------------------------------------------------------------
extern "C" void kernel_launch(void* const* d_in, const int* in_sizes, int n_in,
                              void* d_out, int out_size, void* d_ws, size_t ws_size,
                              hipStream_t stream)
{
    const float* x      = (const float*)d_in[0];
    const float* w_off1 = (const float*)d_in[1];
    const float* b_off1 = (const float*)d_in[2];
    const float* w_dc1  = (const float*)d_in[3];
    const float* g1     = (const float*)d_in[4];
    const float* beta1  = (const float*)d_in[5];
    const float* m1     = (const float*)d_in[6];
    const float* v1     = (const float*)d_in[7];
    const float* w_off2 = (const float*)d_in[8];
    const float* b_off2 = (const float*)d_in[9];
    const float* w_dc2  = (const float*)d_in[10];
    const float* g2     = (const float*)d_in[11];
    const float* beta2  = (const float*)d_in[12];
    const float* m2     = (const float*)d_in[13];
    const float* v2     = (const float*)d_in[14];
    float* out = (float*)d_out;

    char* ws = (char*)d_ws;
    unsigned short* xh    = (unsigned short*)ws;                  // 8,388,608 B
    unsigned short* out1h = (unsigned short*)(ws + 8388608);      // 8,388,608 B
    unsigned short* offh  = (unsigned short*)(ws + 16777216);     // 1,179,648 B
    unsigned short* wpk1  = (unsigned short*)(ws + 17956864);     //   294,912 B
    unsigned short* wpk2  = (unsigned short*)(ws + 18251776);     //   294,912 B
    unsigned short* wpo1  = (unsigned short*)(ws + 18546688);     //    73,728 B
    unsigned short* wpo2  = (unsigned short*)(ws + 18620416);     //    73,728 B

    prep_kernel<<<1952, 256, 0, stream>>>(x, xh, w_dc1, w_dc2, w_off1, w_off2,
                                          wpk1, wpk2, wpo1, wpo2);

    // Layer 1
    off_conv_mfma_kernel<<<512, 256, 0, stream>>>(xh, wpo1, b_off1, offh);
    deform_pc_kernel<<<512, 512, 0, stream>>>(xh, offh, wpk1,
                                              g1, beta1, m1, v1,
                                              nullptr, out1h, nullptr);
    // Layer 2
    off_conv_mfma_kernel<<<512, 256, 0, stream>>>(out1h, wpo2, b_off2, offh);
    deform_pc_kernel<<<512, 512, 0, stream>>>(out1h, offh, wpk2,
                                              g2, beta2, m2, v2,
                                              x, nullptr, out);
}

// Round 12
// 90.650 us; speedup vs baseline: 1.6411x; 1.0101x over previous
//
#include <hip/hip_runtime.h>
#include <hip/hip_bf16.h>

#define CH   128
#define HH   64
#define WW   64
#define OFFC 18

typedef __attribute__((ext_vector_type(8))) short bf16x8;
typedef __attribute__((ext_vector_type(4))) short bf16x4;
typedef __attribute__((ext_vector_type(4))) float f32x4;

static __device__ __forceinline__ unsigned short f2bf(float f) {
    __hip_bfloat16 h = __float2bfloat16(f);
    return *reinterpret_cast<unsigned short*>(&h);
}
static __device__ __forceinline__ float bf2f(unsigned short u) {
    union { unsigned int i; float f; } x; x.i = ((unsigned int)u) << 16;
    return x.f;
}

// ---------------------------------------------------------------------------
// Prep: pack weights + NCHW->NHWC (unchanged).
// ---------------------------------------------------------------------------
__global__ __launch_bounds__(256) void prep_kernel(
    const float* __restrict__ x, unsigned short* __restrict__ xh,
    const float* __restrict__ wdc1, const float* __restrict__ wdc2,
    const float* __restrict__ wof1, const float* __restrict__ wof2,
    unsigned short* __restrict__ wpk1, unsigned short* __restrict__ wpk2,
    unsigned short* __restrict__ wpo1, unsigned short* __restrict__ wpo2)
{
    __shared__ float s[CH][WW + 1];
    int blk = blockIdx.x;
    int tid = threadIdx.x;

    if (blk < 1152) {
        const float* w = (blk < 576) ? wdc1 : wdc2;
        unsigned short* wp = (blk < 576) ? wpk1 : wpk2;
        int id = (blk % 576) * 256 + tid;          // 0..147455
        int j    = id & 7;
        int lane = (id >> 3) & 63;
        int ot   = (id >> 9) & 7;
        int kk   = (id >> 12) & 3;
        int k    = id >> 14;
        int o = ot * 16 + (lane & 15);
        int i = kk * 32 + (lane >> 4) * 8 + j;
        wp[id] = f2bf(w[(o * CH + i) * 9 + k]);
        return;
    }
    if (blk < 1440) {
        const float* w = (blk < 1296) ? wof1 : wof2;
        unsigned short* wp = (blk < 1296) ? wpo1 : wpo2;
        int id = ((blk - 1152) % 144) * 256 + tid; // 0..36863
        int j    = id & 7;
        int lane = (id >> 3) & 63;
        int mt   = (id >> 9) & 1;
        int kk   = (id >> 10) & 3;
        int k    = id >> 12;
        int o = mt * 16 + (lane & 15);
        int i = kk * 32 + (lane >> 4) * 8 + j;
        wp[id] = (o < OFFC) ? f2bf(w[(o * CH + i) * 9 + k]) : (unsigned short)0;
        return;
    }

    int nb = blk - 1440;                     // b*64 + h
    const float* xb = x + ((size_t)(nb >> 6) * CH * HH + (nb & 63)) * WW;

    int c_off = tid >> 4, w0 = (tid & 15) * 4;
    #pragma unroll
    for (int it = 0; it < 8; ++it) {
        int c = it * 16 + c_off;
        float4 vv = *(const float4*)&xb[(size_t)c * HH * WW + w0];
        s[c][w0] = vv.x; s[c][w0 + 1] = vv.y; s[c][w0 + 2] = vv.z; s[c][w0 + 3] = vv.w;
    }
    __syncthreads();

    int w = tid & 63, c0 = (tid >> 6) * 32;
    unsigned short* dst = xh + ((size_t)nb * WW + w) * CH + c0;
    unsigned short tmp[32];
    #pragma unroll
    for (int j = 0; j < 32; ++j) tmp[j] = f2bf(s[c0 + j][w]);
    #pragma unroll
    for (int q = 0; q < 4; ++q)
        *(bf16x8*)(dst + q * 8) = *(const bf16x8*)(tmp + q * 8);
}

// ---------------------------------------------------------------------------
// Offset conv via MFMA implicit GEMM (unchanged).
// ---------------------------------------------------------------------------
__global__ __launch_bounds__(256) void off_conv_mfma_kernel(
    const unsigned short* __restrict__ xh,
    const unsigned short* __restrict__ wpo,
    const float* __restrict__ bias,
    unsigned short* __restrict__ offh)
{
    int wgid = blockIdx.x;                   // 512
    int blk  = (wgid & 7) * 64 + (wgid >> 3);
    int b = blk >> 6, oh = blk & 63;
    int tid = threadIdx.x;
    int lane = tid & 63;
    int nt = tid >> 6;
    int nl = lane & 15;
    int kg = lane >> 4;

    f32x4 acc0 = {0.f, 0.f, 0.f, 0.f}, acc1 = {0.f, 0.f, 0.f, 0.f};
    const unsigned short* xb = xh + (size_t)b * HH * WW * CH;

    for (int k = 0; k < 9; ++k) {
        int ky = k / 3, kx = k - ky * 3;
        int ih = oh - 1 + ky;
        if (ih < 0 || ih >= HH) continue;
        int iw = nt * 16 + nl + kx - 1;
        bool valid = (iw >= 0) && (iw < WW);
        const unsigned short* row = xb + ((size_t)ih * WW + (valid ? iw : 0)) * CH + kg * 8;
        const unsigned short* wk = wpo + (size_t)k * 4096;
        #pragma unroll
        for (int kk = 0; kk < 4; ++kk) {
            bf16x8 bfrag = {0, 0, 0, 0, 0, 0, 0, 0};
            if (valid) bfrag = *(const bf16x8*)(row + kk * 32);
            bf16x8 a0 = *(const bf16x8*)(wk + (kk * 2 + 0) * 512 + lane * 8);
            bf16x8 a1 = *(const bf16x8*)(wk + (kk * 2 + 1) * 512 + lane * 8);
            acc0 = __builtin_amdgcn_mfma_f32_16x16x32_bf16(a0, bfrag, acc0, 0, 0, 0);
            acc1 = __builtin_amdgcn_mfma_f32_16x16x32_bf16(a1, bfrag, acc1, 0, 0, 0);
        }
    }

    int ow = nt * 16 + nl;
    #pragma unroll
    for (int r = 0; r < 4; ++r) {
        int co = kg * 4 + r;
        offh[(((size_t)b * OFFC + co) * HH + oh) * WW + ow] = f2bf(acc0[r] + bias[co]);
    }
    if (kg == 0) {
        #pragma unroll
        for (int r = 0; r < 2; ++r) {
            int co = 16 + r;
            offh[(((size_t)b * OFFC + co) * HH + oh) * WW + ow] = f2bf(acc1[r] + bias[co]);
        }
    }
}

// ---------------------------------------------------------------------------
// Deformable conv — PRODUCER/CONSUMER with DEEP PREFETCH.
// vs r11: producers issue tap-(k+1) gathers right after posting tap k (in
// flight through the consumer-done spin); consumers prefetch tap-(k+1)
// A-fragments right after posting (in flight through the producer-done spin).
// The spin-waits become the latency cover; no barrier ever drains vmcnt.
// ---------------------------------------------------------------------------
#define P_COORD(K, OW, CW, PTR) do {                                          \
    int ky_ = (K) / 3, kx_ = (K) - ky_ * 3;                                   \
    float dy_ = off_s[2 * (K)][OW];                                           \
    float dx_ = off_s[2 * (K) + 1][OW];                                       \
    float ys_ = (float)(oh - 2 + ky_ * 2) + dy_;                              \
    float xs_ = (float)((OW) - 2 + kx_ * 2) + dx_;                            \
    float y0f_ = floorf(ys_), x0f_ = floorf(xs_);                             \
    float fy_ = ys_ - y0f_, fx_ = xs_ - x0f_;                                 \
    int y0_ = (int)y0f_, x0_ = (int)x0f_;                                     \
    int y1_ = y0_ + 1, x1_ = x0_ + 1;                                         \
    bool vy0_ = (y0_ >= 0) & (y0_ < HH), vy1_ = (y1_ >= 0) & (y1_ < HH);      \
    bool vx0_ = (x0_ >= 0) & (x0_ < WW), vx1_ = (x1_ >= 0) & (x1_ < WW);      \
    int y0c_ = min(max(y0_, 0), HH - 1), y1c_ = min(max(y1_, 0), HH - 1);     \
    int x0c_ = min(max(x0_, 0), WW - 1), x1c_ = min(max(x1_, 0), WW - 1);     \
    CW[0] = (1.f - fy_) * (1.f - fx_) * ((vy0_ && vx0_) ? 1.f : 0.f);         \
    CW[1] = (1.f - fy_) * fx_         * ((vy0_ && vx1_) ? 1.f : 0.f);         \
    CW[2] = fy_ * (1.f - fx_)         * ((vy1_ && vx0_) ? 1.f : 0.f);         \
    CW[3] = fy_ * fx_                 * ((vy1_ && vx1_) ? 1.f : 0.f);         \
    PTR[0] = xb + ((size_t)(y0c_ * WW + x0c_)) * CH + cig * 8;                \
    PTR[1] = xb + ((size_t)(y0c_ * WW + x1c_)) * CH + cig * 8;                \
    PTR[2] = xb + ((size_t)(y1c_ * WW + x0c_)) * CH + cig * 8;                \
    PTR[3] = xb + ((size_t)(y1c_ * WW + x1c_)) * CH + cig * 8;                \
} while (0)

#define P_ISSUE(PTR, LD) do {                                                 \
    _Pragma("unroll")                                                         \
    for (int c_ = 0; c_ < 4; ++c_) {                                          \
        LD[0][c_] = *(const bf16x8*)(PTR[c_]);                                \
        LD[1][c_] = *(const bf16x8*)(PTR[c_] + 64);                           \
    }                                                                         \
} while (0)

#define P_BLEND(OW, CW, LD, BUF) do {                                         \
    int swz_ = ((OW) & 7) << 4;                                               \
    _Pragma("unroll")                                                         \
    for (int q_ = 0; q_ < 2; ++q_) {                                          \
        union { bf16x8 v8; unsigned short u[8]; } wu_;                        \
        _Pragma("unroll")                                                     \
        for (int j_ = 0; j_ < 8; ++j_) {                                      \
            float val_ = CW[0] * bf2f((unsigned short)LD[q_][0][j_])          \
                       + CW[1] * bf2f((unsigned short)LD[q_][1][j_])          \
                       + CW[2] * bf2f((unsigned short)LD[q_][2][j_])          \
                       + CW[3] * bf2f((unsigned short)LD[q_][3][j_]);         \
            wu_.u[j_] = f2bf(val_);                                           \
        }                                                                     \
        int byte_ = ((OW) * 256 + (q_ * 64 + cig * 8) * 2) ^ swz_;            \
        *(bf16x8*)((char*)sB[BUF] + byte_) = wu_.v8;                          \
    }                                                                         \
} while (0)

#define C_PREF(K, AP) do {                                                    \
    const unsigned short* wk_ = wpk + (size_t)(K) * 16384;                    \
    _Pragma("unroll")                                                         \
    for (int kk_ = 0; kk_ < 4; ++kk_) {                                       \
        AP[kk_ * 2 + 0] = *(const bf16x8*)(wk_ + (size_t)(kk_ * 8 + 2 * cwi)     * 512 + lane * 8); \
        AP[kk_ * 2 + 1] = *(const bf16x8*)(wk_ + (size_t)(kk_ * 8 + 2 * cwi + 1) * 512 + lane * 8); \
    }                                                                         \
} while (0)

__global__ __launch_bounds__(512, 4) void deform_pc_kernel(
    const unsigned short* __restrict__ xh,    // (B,64,64,128) bf16 (sampled)
    const unsigned short* __restrict__ offh,  // (B,18,64,64) bf16
    const unsigned short* __restrict__ wpk,   // packed A frags [9][4kk][8ot][512]
    const float* __restrict__ g, const float* __restrict__ beta,
    const float* __restrict__ m, const float* __restrict__ v,
    const float* __restrict__ residual,       // layer2 only
    unsigned short* __restrict__ out_h,       // layer1: NHWC bf16 out
    float* __restrict__ out_f)                // layer2: NCHW f32 out
{
    __shared__ unsigned short sB[2][64 * 128]; // 32 KB ring [buf][ow][ci] swz
    __shared__ float off_s[OFFC][WW];          // 4.5 KB offsets (f32)
    __shared__ int flg[4];                     // [0,1]=prod_cnt [2,3]=cons_cnt

    int wgid = blockIdx.x;                    // 512
    int blk  = (wgid & 7) * 64 + (wgid >> 3); // XCD n owns batch n
    int b = blk >> 6, oh = blk & 63;
    int tid = threadIdx.x, lane = tid & 63, wv = tid >> 6;

    const unsigned short* xb = xh + (size_t)b * HH * WW * CH;

    // stage offsets + init flags, single barrier (before any loop loads)
    for (int i = tid; i < OFFC * WW; i += 512) {
        int co = i >> 6, owl = i & 63;
        off_s[co][owl] =
            bf2f(offh[(((size_t)b * OFFC + co) * HH + oh) * WW + owl]);
    }
    if (tid < 4) flg[tid] = 0;
    __syncthreads();

    if (wv < 4) {
        // =================== PRODUCER =====================================
        int s_ow = tid >> 3;                  // 0..31 (also serves +32)
        int cig  = tid & 7;                   // 16B chunk id within pixel

        float cwA[4], cwB[4];
        const unsigned short *ptA[4], *ptB[4];
        bf16x8 ldA[2][4], ldB[2][4];

        // prologue: coords+issue tap 0 (in flight immediately)
        P_COORD(0, s_ow, cwA, ptA);
        P_COORD(0, s_ow + 32, cwB, ptB);
        P_ISSUE(ptA, ldA);
        P_ISSUE(ptB, ldB);

        for (int k = 0; k < 9; ++k) {
            int buf = k & 1;
            if (k >= 2) {
                int tgt = 4 * (k >> 1);       // consumers done with tap k-2
                while (__hip_atomic_load(&flg[2 + buf], __ATOMIC_ACQUIRE,
                                         __HIP_MEMORY_SCOPE_WORKGROUP) < tgt)
                    __builtin_amdgcn_s_sleep(1);
            }
            // blend+write tap k (vmcnt waits only on tap-k loads, the oldest)
            P_BLEND(s_ow,      cwA, ldA, buf);
            P_BLEND(s_ow + 32, cwB, ldB, buf);
            asm volatile("s_waitcnt lgkmcnt(0)" ::: "memory");
            if (lane == 0)
                __hip_atomic_fetch_add(&flg[buf], 1, __ATOMIC_RELEASE,
                                       __HIP_MEMORY_SCOPE_WORKGROUP);
            // deep prefetch: coords+issue tap k+1 — flies through next spin
            if (k < 8) {
                P_COORD(k + 1, s_ow, cwA, ptA);
                P_COORD(k + 1, s_ow + 32, cwB, ptB);
                P_ISSUE(ptA, ldA);
                P_ISSUE(ptB, ldB);
            }
        }
    } else {
        // =================== CONSUMER =====================================
        int cwi = wv - 4;                     // 0..3: o-tiles {2cwi, 2cwi+1}
        f32x4 acc[2][4];
        #pragma unroll
        for (int a = 0; a < 2; ++a)
            #pragma unroll
            for (int q = 0; q < 4; ++q) acc[a][q] = (f32x4){0.f, 0.f, 0.f, 0.f};

        bf16x8 aP[8];
        C_PREF(0, aP);                        // A frags for tap 0 in flight

        for (int k = 0; k < 9; ++k) {
            int buf = k & 1;
            int tgt = 4 * ((k >> 1) + 1);     // producers done with tap k
            while (__hip_atomic_load(&flg[buf], __ATOMIC_ACQUIRE,
                                     __HIP_MEMORY_SCOPE_WORKGROUP) < tgt)
                __builtin_amdgcn_s_sleep(1);

            __builtin_amdgcn_s_setprio(1);
            #pragma unroll
            for (int kk = 0; kk < 4; ++kk) {
                #pragma unroll
                for (int owt = 0; owt < 4; ++owt) {
                    int owl = owt * 16 + (lane & 15);
                    int rbyte = (owl * 256 + (kk * 32 + (lane >> 4) * 8) * 2)
                                ^ ((owl & 7) << 4);
                    bf16x8 bfv = *(const bf16x8*)((const char*)sB[buf] + rbyte);
                    acc[0][owt] = __builtin_amdgcn_mfma_f32_16x16x32_bf16(
                                      aP[kk * 2 + 0], bfv, acc[0][owt], 0, 0, 0);
                    acc[1][owt] = __builtin_amdgcn_mfma_f32_16x16x32_bf16(
                                      aP[kk * 2 + 1], bfv, acc[1][owt], 0, 0, 0);
                }
            }
            __builtin_amdgcn_s_setprio(0);
            asm volatile("s_waitcnt lgkmcnt(0)" ::: "memory");
            if (lane == 0)
                __hip_atomic_fetch_add(&flg[2 + buf], 1, __ATOMIC_RELEASE,
                                       __HIP_MEMORY_SCOPE_WORKGROUP);
            // deep prefetch: A frags for tap k+1 — fly through next spin
            if (k < 8) C_PREF(k + 1, aP);
        }

        // ---- epilogue (consumers hold all 128 o across 4 waves) --------
        #pragma unroll
        for (int otl = 0; otl < 2; ++otl) {
            int ob = (2 * cwi + otl) * 16 + (lane >> 4) * 4;
            float inv[4], sh[4];
            #pragma unroll
            for (int r = 0; r < 4; ++r) {
                int o = ob + r;
                float iv = g[o] / sqrtf(v[o] + 1e-5f);
                inv[r] = iv; sh[r] = beta[o] - m[o] * iv;
            }
            if (out_h != nullptr) {
                #pragma unroll
                for (int owt = 0; owt < 4; ++owt) {
                    int ow = owt * 16 + (lane & 15);
                    union { bf16x4 v4; unsigned short u[4]; } pk;
                    #pragma unroll
                    for (int r = 0; r < 4; ++r) {
                        float val = acc[otl][owt][r] * inv[r] + sh[r];
                        pk.u[r] = f2bf(fmaxf(val, 0.f));
                    }
                    *(bf16x4*)(out_h + ((size_t)(b * HH + oh) * WW + ow) * CH + ob) = pk.v4;
                }
            } else {
                #pragma unroll
                for (int r = 0; r < 4; ++r) {
                    int o = ob + r;
                    #pragma unroll
                    for (int owt = 0; owt < 4; ++owt) {
                        int ow = owt * 16 + (lane & 15);
                        size_t idx = (((size_t)b * CH + o) * HH + oh) * WW + ow;
                        float val = acc[otl][owt][r] * inv[r] + sh[r] + residual[idx];
                        out_f[idx] = fmaxf(val, 0.f);
                    }
                }
            }
        }
    }
}

// ---------------------------------------------------------------------------
extern "C" void kernel_launch(void* const* d_in, const int* in_sizes, int n_in,
                              void* d_out, int out_size, void* d_ws, size_t ws_size,
                              hipStream_t stream)
{
    const float* x      = (const float*)d_in[0];
    const float* w_off1 = (const float*)d_in[1];
    const float* b_off1 = (const float*)d_in[2];
    const float* w_dc1  = (const float*)d_in[3];
    const float* g1     = (const float*)d_in[4];
    const float* beta1  = (const float*)d_in[5];
    const float* m1     = (const float*)d_in[6];
    const float* v1     = (const float*)d_in[7];
    const float* w_off2 = (const float*)d_in[8];
    const float* b_off2 = (const float*)d_in[9];
    const float* w_dc2  = (const float*)d_in[10];
    const float* g2     = (const float*)d_in[11];
    const float* beta2  = (const float*)d_in[12];
    const float* m2     = (const float*)d_in[13];
    const float* v2     = (const float*)d_in[14];
    float* out = (float*)d_out;

    char* ws = (char*)d_ws;
    unsigned short* xh    = (unsigned short*)ws;                  // 8,388,608 B
    unsigned short* out1h = (unsigned short*)(ws + 8388608);      // 8,388,608 B
    unsigned short* offh  = (unsigned short*)(ws + 16777216);     // 1,179,648 B
    unsigned short* wpk1  = (unsigned short*)(ws + 17956864);     //   294,912 B
    unsigned short* wpk2  = (unsigned short*)(ws + 18251776);     //   294,912 B
    unsigned short* wpo1  = (unsigned short*)(ws + 18546688);     //    73,728 B
    unsigned short* wpo2  = (unsigned short*)(ws + 18620416);     //    73,728 B

    prep_kernel<<<1952, 256, 0, stream>>>(x, xh, w_dc1, w_dc2, w_off1, w_off2,
                                          wpk1, wpk2, wpo1, wpo2);

    // Layer 1
    off_conv_mfma_kernel<<<512, 256, 0, stream>>>(xh, wpo1, b_off1, offh);
    deform_pc_kernel<<<512, 512, 0, stream>>>(xh, offh, wpk1,
                                              g1, beta1, m1, v1,
                                              nullptr, out1h, nullptr);
    // Layer 2
    off_conv_mfma_kernel<<<512, 256, 0, stream>>>(out1h, wpo2, b_off2, offh);
    deform_pc_kernel<<<512, 512, 0, stream>>>(out1h, offh, wpk2,
                                              g2, beta2, m2, v2,
                                              x, nullptr, out);
}